// Round 1
// baseline (1240.474 us; speedup 1.0000x reference)
//
#include <hip/hip_runtime.h>
#include <hip/hip_bf16.h>

#define EMBED 1024
#define NTOK  4096

#define BM 128
#define BN 128
#define BK 16

// ---------------------------------------------------------------------------
// gemm_nn: C[M,N] = scale * A[M,K] @ B[K,N], all row-major fp32.
// grid = (N/BN, M/BM), block = 256 (tx=t&15, ty=t>>4), 8x8 micro-tile.
// ---------------------------------------------------------------------------
__global__ __launch_bounds__(256) void gemm_nn(const float* __restrict__ A,
                                               const float* __restrict__ B,
                                               float* __restrict__ C,
                                               int K, int lda, int ldb, int ldc,
                                               float scale) {
    __shared__ float As[BK][BM + 4];
    __shared__ float Bs[BK][BN + 4];

    const int t  = threadIdx.x;
    const int tx = t & 15;
    const int ty = t >> 4;
    const int m0 = blockIdx.y * BM;
    const int n0 = blockIdx.x * BN;

    float acc[8][8];
#pragma unroll
    for (int i = 0; i < 8; ++i)
#pragma unroll
        for (int j = 0; j < 8; ++j) acc[i][j] = 0.f;

    for (int k0 = 0; k0 < K; k0 += BK) {
        // A tile: 128 rows x 16 k, stored transposed As[k][m]
#pragma unroll
        for (int p = 0; p < 2; ++p) {
            const int m  = (t >> 2) + p * 64;
            const int k4 = (t & 3) * 4;
            const float4 a = *(const float4*)&A[(size_t)(m0 + m) * lda + k0 + k4];
            As[k4 + 0][m] = a.x;
            As[k4 + 1][m] = a.y;
            As[k4 + 2][m] = a.z;
            As[k4 + 3][m] = a.w;
        }
        // B tile: 16 k x 128 n, stored direct Bs[k][n]
#pragma unroll
        for (int p = 0; p < 2; ++p) {
            const int k  = (t >> 5) + p * 8;
            const int n4 = (t & 31) * 4;
            const float4 b = *(const float4*)&B[(size_t)(k0 + k) * ldb + n0 + n4];
            *(float4*)&Bs[k][n4] = b;
        }
        __syncthreads();

#pragma unroll
        for (int k = 0; k < BK; ++k) {
            const float4 a0 = *(const float4*)&As[k][ty * 8];
            const float4 a1 = *(const float4*)&As[k][ty * 8 + 4];
            const float4 b0 = *(const float4*)&Bs[k][tx * 4];
            const float4 b1 = *(const float4*)&Bs[k][64 + tx * 4];
            const float av[8] = {a0.x, a0.y, a0.z, a0.w, a1.x, a1.y, a1.z, a1.w};
            const float bv[8] = {b0.x, b0.y, b0.z, b0.w, b1.x, b1.y, b1.z, b1.w};
#pragma unroll
            for (int i = 0; i < 8; ++i)
#pragma unroll
                for (int j = 0; j < 8; ++j)
                    acc[i][j] = fmaf(av[i], bv[j], acc[i][j]);
        }
        __syncthreads();
    }

#pragma unroll
    for (int i = 0; i < 8; ++i) {
        const int row = m0 + ty * 8 + i;
        float4 c0, c1;
        c0.x = acc[i][0] * scale; c0.y = acc[i][1] * scale;
        c0.z = acc[i][2] * scale; c0.w = acc[i][3] * scale;
        c1.x = acc[i][4] * scale; c1.y = acc[i][5] * scale;
        c1.z = acc[i][6] * scale; c1.w = acc[i][7] * scale;
        *(float4*)&C[(size_t)row * ldc + n0 + tx * 4]      = c0;
        *(float4*)&C[(size_t)row * ldc + n0 + 64 + tx * 4] = c1;
    }
}

// ---------------------------------------------------------------------------
// gemm_nt: C[M,N] = scale * A[M,K] @ B^T where B is [N,K] row-major.
// ---------------------------------------------------------------------------
__global__ __launch_bounds__(256) void gemm_nt(const float* __restrict__ A,
                                               const float* __restrict__ B,
                                               float* __restrict__ C,
                                               int K, int lda, int ldb, int ldc,
                                               float scale) {
    __shared__ float As[BK][BM + 4];
    __shared__ float Bs[BK][BN + 4];

    const int t  = threadIdx.x;
    const int tx = t & 15;
    const int ty = t >> 4;
    const int m0 = blockIdx.y * BM;
    const int n0 = blockIdx.x * BN;

    float acc[8][8];
#pragma unroll
    for (int i = 0; i < 8; ++i)
#pragma unroll
        for (int j = 0; j < 8; ++j) acc[i][j] = 0.f;

    for (int k0 = 0; k0 < K; k0 += BK) {
#pragma unroll
        for (int p = 0; p < 2; ++p) {
            const int m  = (t >> 2) + p * 64;
            const int k4 = (t & 3) * 4;
            const float4 a = *(const float4*)&A[(size_t)(m0 + m) * lda + k0 + k4];
            As[k4 + 0][m] = a.x;
            As[k4 + 1][m] = a.y;
            As[k4 + 2][m] = a.z;
            As[k4 + 3][m] = a.w;
        }
        // B tile from [N,K] row-major: read along k (contiguous), store Bs[k][n]
#pragma unroll
        for (int p = 0; p < 2; ++p) {
            const int n  = (t >> 2) + p * 64;
            const int k4 = (t & 3) * 4;
            const float4 b = *(const float4*)&B[(size_t)(n0 + n) * ldb + k0 + k4];
            Bs[k4 + 0][n] = b.x;
            Bs[k4 + 1][n] = b.y;
            Bs[k4 + 2][n] = b.z;
            Bs[k4 + 3][n] = b.w;
        }
        __syncthreads();

#pragma unroll
        for (int k = 0; k < BK; ++k) {
            const float4 a0 = *(const float4*)&As[k][ty * 8];
            const float4 a1 = *(const float4*)&As[k][ty * 8 + 4];
            const float4 b0 = *(const float4*)&Bs[k][tx * 4];
            const float4 b1 = *(const float4*)&Bs[k][64 + tx * 4];
            const float av[8] = {a0.x, a0.y, a0.z, a0.w, a1.x, a1.y, a1.z, a1.w};
            const float bv[8] = {b0.x, b0.y, b0.z, b0.w, b1.x, b1.y, b1.z, b1.w};
#pragma unroll
            for (int i = 0; i < 8; ++i)
#pragma unroll
                for (int j = 0; j < 8; ++j)
                    acc[i][j] = fmaf(av[i], bv[j], acc[i][j]);
        }
        __syncthreads();
    }

#pragma unroll
    for (int i = 0; i < 8; ++i) {
        const int row = m0 + ty * 8 + i;
        float4 c0, c1;
        c0.x = acc[i][0] * scale; c0.y = acc[i][1] * scale;
        c0.z = acc[i][2] * scale; c0.w = acc[i][3] * scale;
        c1.x = acc[i][4] * scale; c1.y = acc[i][5] * scale;
        c1.z = acc[i][6] * scale; c1.w = acc[i][7] * scale;
        *(float4*)&C[(size_t)row * ldc + n0 + tx * 4]      = c0;
        *(float4*)&C[(size_t)row * ldc + n0 + 64 + tx * 4] = c1;
    }
}

// ---------------------------------------------------------------------------
// Row softmax, in place. One block (256 thr) per row of S[NROW, 4096].
// Row held in registers (16 floats/thread).
// ---------------------------------------------------------------------------
__global__ __launch_bounds__(256) void softmax_rows(float* __restrict__ S) {
    const int t = threadIdx.x;
    float* p = S + (size_t)blockIdx.x * NTOK;

    float v[16];
#pragma unroll
    for (int i = 0; i < 4; ++i) {
        const float4 x = *(const float4*)&p[(t + 256 * i) * 4];
        v[i * 4 + 0] = x.x; v[i * 4 + 1] = x.y;
        v[i * 4 + 2] = x.z; v[i * 4 + 3] = x.w;
    }

    // max
    float m = -3.4e38f;
#pragma unroll
    for (int j = 0; j < 16; ++j) m = fmaxf(m, v[j]);
#pragma unroll
    for (int off = 32; off >= 1; off >>= 1) m = fmaxf(m, __shfl_xor(m, off, 64));
    __shared__ float red[4];
    const int wave = t >> 6;
    if ((t & 63) == 0) red[wave] = m;
    __syncthreads();
    m = fmaxf(fmaxf(red[0], red[1]), fmaxf(red[2], red[3]));
    __syncthreads();

    // exp + sum
    float s = 0.f;
#pragma unroll
    for (int j = 0; j < 16; ++j) {
        v[j] = __expf(v[j] - m);
        s += v[j];
    }
#pragma unroll
    for (int off = 32; off >= 1; off >>= 1) s += __shfl_xor(s, off, 64);
    __shared__ float red2[4];
    if ((t & 63) == 0) red2[wave] = s;
    __syncthreads();
    s = (red2[0] + red2[1]) + (red2[2] + red2[3]);
    const float inv = 1.0f / s;

#pragma unroll
    for (int i = 0; i < 4; ++i) {
        float4 x;
        x.x = v[i * 4 + 0] * inv; x.y = v[i * 4 + 1] * inv;
        x.z = v[i * 4 + 2] * inv; x.w = v[i * 4 + 3] * inv;
        *(float4*)&p[(t + 256 * i) * 4] = x;
    }
}

extern "C" void kernel_launch(void* const* d_in, const int* in_sizes, int n_in,
                              void* d_out, int out_size, void* d_ws, size_t ws_size,
                              hipStream_t stream) {
    const float* X  = (const float*)d_in[0];  // [4096,1024]
    const float* Wq = (const float*)d_in[1];  // [1024,1024]
    const float* Wk = (const float*)d_in[2];  // [1024,1024]
    float* out = (float*)d_out;               // [4096,1024]

    float* Q = (float*)d_ws;                  // 4096*1024
    float* K = Q + (size_t)NTOK * EMBED;      // 4096*1024
    float* S = K + (size_t)NTOK * EMBED;      // 4096*4096

    const float scale = 0.03125f;             // 1/sqrt(1024)

    // Q = X @ Wq ; K = X @ Wk
    dim3 gProj(EMBED / BN, NTOK / BM);
    gemm_nn<<<gProj, 256, 0, stream>>>(X, Wq, Q, EMBED, EMBED, EMBED, EMBED, 1.0f);
    gemm_nn<<<gProj, 256, 0, stream>>>(X, Wk, K, EMBED, EMBED, EMBED, EMBED, 1.0f);

    // S = (Q @ K^T) * scale
    dim3 gScore(NTOK / BN, NTOK / BM);
    gemm_nt<<<gScore, 256, 0, stream>>>(Q, K, S, EMBED, EMBED, EMBED, NTOK, scale);

    // softmax rows in place
    softmax_rows<<<NTOK, 256, 0, stream>>>(S);

    // out = S @ X
    dim3 gOut(EMBED / BN, NTOK / BM);
    gemm_nn<<<gOut, 256, 0, stream>>>(S, X, out, NTOK, NTOK, EMBED, EMBED, 1.0f);
}

// Round 2
// 357.403 us; speedup vs baseline: 3.4708x; 3.4708x over previous
//
#include <hip/hip_runtime.h>

#define EMBED 1024
#define NTOK  4096

typedef short  s16x8 __attribute__((ext_vector_type(8)));
typedef float  f32x4 __attribute__((ext_vector_type(4)));

// ---- bf16 helpers (RNE, bit ops — no header-API dependence) -----------------
__device__ __forceinline__ unsigned short f2bf(float f) {
    unsigned int u = __float_as_uint(f);
    u = (u + 0x7FFFu + ((u >> 16) & 1u)) >> 16;
    return (unsigned short)u;
}
__device__ __forceinline__ float bf2f(unsigned short h) {
    return __uint_as_float(((unsigned int)h) << 16);
}

// ---- async 16B global->LDS -------------------------------------------------
__device__ __forceinline__ void async16(const void* g, void* l) {
    __builtin_amdgcn_global_load_lds(
        (const __attribute__((address_space(1))) unsigned int*)g,
        (__attribute__((address_space(3))) unsigned int*)l, 16, 0, 0);
}

// Stage ROWS x 32 bf16 tile (row-major, swizzled 16B chunks) into LDS.
// g points at element (row0, k0); ld in elements. LDS rows are 64B, chunk slot
// s holds global chunk kc = (s - (row%16)/2) & 3.
template<int ROWS>
__device__ __forceinline__ void stage_tile(const unsigned short* __restrict__ g,
                                           int ld, short* lds, int wave, int lane) {
#pragma unroll
    for (int r = 0; r < ROWS / 64; ++r) {
        const int row0 = (wave * (ROWS / 64) + r) * 16;   // wave-uniform
        const int r_loc = lane >> 2;
        const int kc = (lane - (lane >> 3)) & 3;          // (slot - r_loc/2) & 3
        const unsigned short* gp = g + (size_t)(row0 + r_loc) * ld + kc * 8;
        short* lp = lds + row0 * 32;                      // wave-uniform base
        async16(gp, lp);
    }
}

// Read one 16x32 MFMA fragment (A or B operand) from a staged tile.
__device__ __forceinline__ s16x8 frag_ld(const short* lds, int row, int kc) {
    const int slot = (kc + ((row & 15) >> 1)) & 3;
    return *(const s16x8*)(lds + row * 32 + slot * 8);
}

// ---------------------------------------------------------------------------
// MFMA GEMM: C[M,N] = scale * A[M,K] @ B[N,K]^T  (bf16 in, fp32 acc)
// SPLIT==3: A=(Ahi+Alo), B=(Bhi+Blo), 3-pass (hh + hl + lh).
// EPI==0: write fp32 C. EPI==1: write split bf16 (Chi, Clo).
// Block 256 thr = 4 waves in 2x2; wave tile (BM/2)x(BN/2).
// ---------------------------------------------------------------------------
template<int BM, int BN, int SPLIT, int EPI>
__global__ __launch_bounds__(256) void gemm_mfma(
        const unsigned short* __restrict__ Ahi, const unsigned short* __restrict__ Alo,
        const unsigned short* __restrict__ Bhi, const unsigned short* __restrict__ Blo,
        float* __restrict__ C, unsigned short* __restrict__ Chi,
        unsigned short* __restrict__ Clo,
        int K, int lda, int ldb, int ldc, float scale)
{
    constexpr int TM = BM / 2, TN = BN / 2;
    constexpr int IM = TM / 16, IN = TN / 16;

    __shared__ __align__(16) short As_hi[BM * 32];
    __shared__ __align__(16) short Bs_hi[BN * 32];
    __shared__ __align__(16) short As_lo[SPLIT == 3 ? BM * 32 : 8];
    __shared__ __align__(16) short Bs_lo[SPLIT == 3 ? BN * 32 : 8];

    const int t = threadIdx.x;
    const int lane = t & 63, wave = t >> 6;
    const int wm = wave >> 1, wn = wave & 1;
    const int m0 = blockIdx.y * BM, n0 = blockIdx.x * BN;

    f32x4 acc[IM][IN];
#pragma unroll
    for (int i = 0; i < IM; ++i)
#pragma unroll
        for (int j = 0; j < IN; ++j)
#pragma unroll
            for (int r = 0; r < 4; ++r) acc[i][j][r] = 0.f;

    const unsigned short* ah_g = Ahi + (size_t)m0 * lda;
    const unsigned short* bh_g = Bhi + (size_t)n0 * ldb;
    const unsigned short* al_g = (SPLIT == 3) ? Alo + (size_t)m0 * lda : nullptr;
    const unsigned short* bl_g = (SPLIT == 3) ? Blo + (size_t)n0 * ldb : nullptr;

    const int kc = lane >> 4;
    const int rr = lane & 15;

    for (int k0 = 0; k0 < K; k0 += 32) {
        stage_tile<BM>(ah_g + k0, lda, As_hi, wave, lane);
        stage_tile<BN>(bh_g + k0, ldb, Bs_hi, wave, lane);
        if constexpr (SPLIT == 3) {
            stage_tile<BM>(al_g + k0, lda, As_lo, wave, lane);
            stage_tile<BN>(bl_g + k0, ldb, Bs_lo, wave, lane);
        }
        __syncthreads();

        s16x8 ah[IM], bh[IN], al[IM], bl[IN];
#pragma unroll
        for (int i = 0; i < IM; ++i) ah[i] = frag_ld(As_hi, wm * TM + i * 16 + rr, kc);
#pragma unroll
        for (int j = 0; j < IN; ++j) bh[j] = frag_ld(Bs_hi, wn * TN + j * 16 + rr, kc);
        if constexpr (SPLIT == 3) {
#pragma unroll
            for (int i = 0; i < IM; ++i) al[i] = frag_ld(As_lo, wm * TM + i * 16 + rr, kc);
#pragma unroll
            for (int j = 0; j < IN; ++j) bl[j] = frag_ld(Bs_lo, wn * TN + j * 16 + rr, kc);
        }

#pragma unroll
        for (int i = 0; i < IM; ++i)
#pragma unroll
            for (int j = 0; j < IN; ++j)
                acc[i][j] = __builtin_amdgcn_mfma_f32_16x16x32_bf16(ah[i], bh[j], acc[i][j], 0, 0, 0);
        if constexpr (SPLIT == 3) {
#pragma unroll
            for (int i = 0; i < IM; ++i)
#pragma unroll
                for (int j = 0; j < IN; ++j)
                    acc[i][j] = __builtin_amdgcn_mfma_f32_16x16x32_bf16(ah[i], bl[j], acc[i][j], 0, 0, 0);
#pragma unroll
            for (int i = 0; i < IM; ++i)
#pragma unroll
                for (int j = 0; j < IN; ++j)
                    acc[i][j] = __builtin_amdgcn_mfma_f32_16x16x32_bf16(al[i], bh[j], acc[i][j], 0, 0, 0);
        }
        __syncthreads();
    }

    // Epilogue: C/D layout col=lane&15, row=(lane>>4)*4+reg
    const int lr = lane >> 4;
    const int lc = lane & 15;
#pragma unroll
    for (int i = 0; i < IM; ++i)
#pragma unroll
        for (int j = 0; j < IN; ++j)
#pragma unroll
            for (int r = 0; r < 4; ++r) {
                const int row = m0 + wm * TM + i * 16 + lr * 4 + r;
                const int col = n0 + wn * TN + j * 16 + lc;
                const float v = acc[i][j][r] * scale;
                const size_t idx = (size_t)row * ldc + col;
                if constexpr (EPI == 0) {
                    C[idx] = v;
                } else {
                    const unsigned short h = f2bf(v);
                    Chi[idx] = h;
                    Clo[idx] = f2bf(v - bf2f(h));
                }
            }
}

// ---------------------------------------------------------------------------
// Elementwise fp32 -> (hi, lo) bf16 split.
// ---------------------------------------------------------------------------
__global__ __launch_bounds__(256) void split_convert(const float4* __restrict__ in,
                                                     ushort4* __restrict__ hi,
                                                     ushort4* __restrict__ lo, int n4) {
    for (int idx = blockIdx.x * 256 + threadIdx.x; idx < n4; idx += gridDim.x * 256) {
        const float4 v = in[idx];
        ushort4 h, l;
        h.x = f2bf(v.x); l.x = f2bf(v.x - bf2f(h.x));
        h.y = f2bf(v.y); l.y = f2bf(v.y - bf2f(h.y));
        h.z = f2bf(v.z); l.z = f2bf(v.z - bf2f(h.z));
        h.w = f2bf(v.w); l.w = f2bf(v.w - bf2f(h.w));
        hi[idx] = h; lo[idx] = l;
    }
}

// ---------------------------------------------------------------------------
// Transpose fp32 [R,C] -> bf16 [C,R] (hi, optionally lo). Block 256 (32x8).
// ---------------------------------------------------------------------------
template<bool WRITE_LO>
__global__ __launch_bounds__(256) void transpose_split(const float* __restrict__ in,
                                                       unsigned short* __restrict__ hi,
                                                       unsigned short* __restrict__ lo,
                                                       int R, int Cc) {
    __shared__ float tile[32][33];
    const int tx = threadIdx.x & 31, ty = threadIdx.x >> 5;
    const int r0 = blockIdx.y * 32, c0 = blockIdx.x * 32;
#pragma unroll
    for (int p = 0; p < 4; ++p)
        tile[ty + p * 8][tx] = in[(size_t)(r0 + ty + p * 8) * Cc + c0 + tx];
    __syncthreads();
#pragma unroll
    for (int p = 0; p < 4; ++p) {
        const float v = tile[tx][ty + p * 8];
        const size_t idx = (size_t)(c0 + ty + p * 8) * R + r0 + tx;
        const unsigned short h = f2bf(v);
        hi[idx] = h;
        if constexpr (WRITE_LO) lo[idx] = f2bf(v - bf2f(h));
    }
}

// ---------------------------------------------------------------------------
// Row softmax: read fp32 S row, write bf16 row. One block per row.
// ---------------------------------------------------------------------------
__global__ __launch_bounds__(256) void softmax_rows(const float* __restrict__ S,
                                                    unsigned short* __restrict__ Sb) {
    const int t = threadIdx.x;
    const float* p = S + (size_t)blockIdx.x * NTOK;

    float v[16];
#pragma unroll
    for (int i = 0; i < 4; ++i) {
        const float4 x = *(const float4*)&p[(t + 256 * i) * 4];
        v[i * 4 + 0] = x.x; v[i * 4 + 1] = x.y;
        v[i * 4 + 2] = x.z; v[i * 4 + 3] = x.w;
    }

    float m = -3.4e38f;
#pragma unroll
    for (int j = 0; j < 16; ++j) m = fmaxf(m, v[j]);
#pragma unroll
    for (int off = 32; off >= 1; off >>= 1) m = fmaxf(m, __shfl_xor(m, off, 64));
    __shared__ float red[4], red2[4];
    const int wave = t >> 6;
    if ((t & 63) == 0) red[wave] = m;
    __syncthreads();
    m = fmaxf(fmaxf(red[0], red[1]), fmaxf(red[2], red[3]));
    __syncthreads();

    float s = 0.f;
#pragma unroll
    for (int j = 0; j < 16; ++j) {
        v[j] = __expf(v[j] - m);
        s += v[j];
    }
#pragma unroll
    for (int off = 32; off >= 1; off >>= 1) s += __shfl_xor(s, off, 64);
    if ((t & 63) == 0) red2[wave] = s;
    __syncthreads();
    s = (red2[0] + red2[1]) + (red2[2] + red2[3]);
    const float inv = 1.0f / s;

    unsigned short* q = Sb + (size_t)blockIdx.x * NTOK;
#pragma unroll
    for (int i = 0; i < 4; ++i) {
        ushort4 o;
        o.x = f2bf(v[i * 4 + 0] * inv);
        o.y = f2bf(v[i * 4 + 1] * inv);
        o.z = f2bf(v[i * 4 + 2] * inv);
        o.w = f2bf(v[i * 4 + 3] * inv);
        *(ushort4*)&q[(t + 256 * i) * 4] = o;
    }
}

extern "C" void kernel_launch(void* const* d_in, const int* in_sizes, int n_in,
                              void* d_out, int out_size, void* d_ws, size_t ws_size,
                              hipStream_t stream) {
    const float* X  = (const float*)d_in[0];
    const float* Wq = (const float*)d_in[1];
    const float* Wk = (const float*)d_in[2];
    float* out = (float*)d_out;

    char* ws = (char*)d_ws;
    const size_t MB = 1024 * 1024;
    // Region B [0,32MB): Q/K splits; Sb (32MB) aliases after scores.
    unsigned short* Qhi = (unsigned short*)(ws + 0 * MB);
    unsigned short* Qlo = (unsigned short*)(ws + 8 * MB);
    unsigned short* Khi = (unsigned short*)(ws + 16 * MB);
    unsigned short* Klo = (unsigned short*)(ws + 24 * MB);
    unsigned short* Sb  = (unsigned short*)(ws + 0 * MB);
    // Region C [32MB,96MB): S fp32; Xt (8MB) aliases after softmax.
    float*          S   = (float*)(ws + 32 * MB);
    unsigned short* Xt  = (unsigned short*)(ws + 32 * MB);
    // Region A [32MB,56MB): X/W splits (dead before S is written).
    unsigned short* Xhi = (unsigned short*)(ws + 32 * MB);
    unsigned short* Xlo = (unsigned short*)(ws + 40 * MB);
    unsigned short* Wqhi = (unsigned short*)(ws + 48 * MB);
    unsigned short* Wqlo = (unsigned short*)(ws + 50 * MB);
    unsigned short* Wkhi = (unsigned short*)(ws + 52 * MB);
    unsigned short* Wklo = (unsigned short*)(ws + 54 * MB);

    // 1) split X
    split_convert<<<4096, 256, 0, stream>>>((const float4*)X, (ushort4*)Xhi,
                                            (ushort4*)Xlo, NTOK * EMBED / 4);
    // 2) transpose+split Wq, Wk -> [N,K]
    transpose_split<true><<<dim3(32, 32), 256, 0, stream>>>(Wq, Wqhi, Wqlo, EMBED, EMBED);
    transpose_split<true><<<dim3(32, 32), 256, 0, stream>>>(Wk, Wkhi, Wklo, EMBED, EMBED);

    // 3) Q = X@Wq, K = X@Wk (split 3-pass, split epilogue)
    gemm_mfma<128, 64, 3, 1><<<dim3(16, 32), 256, 0, stream>>>(
        Xhi, Xlo, Wqhi, Wqlo, nullptr, Qhi, Qlo, EMBED, EMBED, EMBED, EMBED, 1.0f);
    gemm_mfma<128, 64, 3, 1><<<dim3(16, 32), 256, 0, stream>>>(
        Xhi, Xlo, Wkhi, Wklo, nullptr, Khi, Klo, EMBED, EMBED, EMBED, EMBED, 1.0f);

    // 4) S = (Q @ K^T) / 32  (split 3-pass, fp32 out)
    gemm_mfma<128, 128, 3, 0><<<dim3(32, 32), 256, 0, stream>>>(
        Qhi, Qlo, Khi, Klo, S, nullptr, nullptr, EMBED, EMBED, EMBED, NTOK, 0.03125f);

    // 5) softmax rows -> bf16 Sb (over dead Q/K region)
    softmax_rows<<<NTOK, 256, 0, stream>>>(S, Sb);

    // 6) Xt = X^T bf16 (over dead S region)
    transpose_split<false><<<dim3(32, 128), 256, 0, stream>>>(X, Xt, nullptr, NTOK, EMBED);

    // 7) out = Sb @ Xt^T (plain bf16, fp32 out)
    gemm_mfma<128, 64, 1, 0><<<dim3(16, 32), 256, 0, stream>>>(
        Sb, nullptr, Xt, nullptr, out, nullptr, nullptr, NTOK, NTOK, NTOK, EMBED, 1.0f);
}

// Round 3
// 209.938 us; speedup vs baseline: 5.9088x; 1.7024x over previous
//
#include <hip/hip_runtime.h>

#define EMBED 1024
#define NTOK  4096

typedef short  s16x8 __attribute__((ext_vector_type(8)));
typedef float  f32x4 __attribute__((ext_vector_type(4)));

// ---- bf16 helpers (RNE) ----------------------------------------------------
__device__ __forceinline__ unsigned short f2bf(float f) {
    unsigned int u = __float_as_uint(f);
    u = (u + 0x7FFFu + ((u >> 16) & 1u)) >> 16;
    return (unsigned short)u;
}
__device__ __forceinline__ float bf2f(unsigned short h) {
    return __uint_as_float(((unsigned int)h) << 16);
}

// ---- async 16B global->LDS -------------------------------------------------
__device__ __forceinline__ void async16(const void* g, void* l) {
    __builtin_amdgcn_global_load_lds(
        (const __attribute__((address_space(1))) unsigned int*)g,
        (__attribute__((address_space(3))) unsigned int*)l, 16, 0, 0);
}

// Stage ROWS x 32 bf16 tile (row-major, swizzled 16B chunks) into LDS.
template<int ROWS>
__device__ __forceinline__ void stage_tile(const unsigned short* __restrict__ g,
                                           int ld, short* lds, int wave, int lane) {
#pragma unroll
    for (int r = 0; r < ROWS / 64; ++r) {
        const int row0 = (wave * (ROWS / 64) + r) * 16;   // wave-uniform
        const int r_loc = lane >> 2;
        const int kc = (lane - (lane >> 3)) & 3;          // (slot - r_loc/2) & 3
        const unsigned short* gp = g + (size_t)(row0 + r_loc) * ld + kc * 8;
        short* lp = lds + row0 * 32;                      // wave-uniform base
        async16(gp, lp);
    }
}

__device__ __forceinline__ s16x8 frag_ld(const short* lds, int row, int kc) {
    const int slot = (kc + ((row & 15) >> 1)) & 3;
    return *(const s16x8*)(lds + row * 32 + slot * 8);
}

// ---------------------------------------------------------------------------
// MFMA GEMM: C[M,N] = scale * A[M,K] @ B[N,K]^T  (bf16 in, fp32 acc)
// SPLIT==3: 3-pass split-bf16 (hh + hl + lh).
// EPI==0: fp32 C.  EPI==1: split bf16 (Chi,Clo).  EPI==2: fp32 C + bf16 Chi.
// ---------------------------------------------------------------------------
template<int BM, int BN, int SPLIT, int EPI>
__global__ __launch_bounds__(256) void gemm_mfma(
        const unsigned short* __restrict__ Ahi, const unsigned short* __restrict__ Alo,
        const unsigned short* __restrict__ Bhi, const unsigned short* __restrict__ Blo,
        float* __restrict__ C, unsigned short* __restrict__ Chi,
        unsigned short* __restrict__ Clo,
        int K, int lda, int ldb, int ldc, float scale)
{
    constexpr int TM = BM / 2, TN = BN / 2;
    constexpr int IM = TM / 16, IN = TN / 16;

    __shared__ __align__(16) short As_hi[BM * 32];
    __shared__ __align__(16) short Bs_hi[BN * 32];
    __shared__ __align__(16) short As_lo[SPLIT == 3 ? BM * 32 : 8];
    __shared__ __align__(16) short Bs_lo[SPLIT == 3 ? BN * 32 : 8];

    const int t = threadIdx.x;
    const int lane = t & 63, wave = t >> 6;
    const int wm = wave >> 1, wn = wave & 1;
    const int m0 = blockIdx.y * BM, n0 = blockIdx.x * BN;

    f32x4 acc[IM][IN];
#pragma unroll
    for (int i = 0; i < IM; ++i)
#pragma unroll
        for (int j = 0; j < IN; ++j)
#pragma unroll
            for (int r = 0; r < 4; ++r) acc[i][j][r] = 0.f;

    const unsigned short* ah_g = Ahi + (size_t)m0 * lda;
    const unsigned short* bh_g = Bhi + (size_t)n0 * ldb;
    const unsigned short* al_g = (SPLIT == 3) ? Alo + (size_t)m0 * lda : nullptr;
    const unsigned short* bl_g = (SPLIT == 3) ? Blo + (size_t)n0 * ldb : nullptr;

    const int kc = lane >> 4;
    const int rr = lane & 15;

    for (int k0 = 0; k0 < K; k0 += 32) {
        stage_tile<BM>(ah_g + k0, lda, As_hi, wave, lane);
        stage_tile<BN>(bh_g + k0, ldb, Bs_hi, wave, lane);
        if constexpr (SPLIT == 3) {
            stage_tile<BM>(al_g + k0, lda, As_lo, wave, lane);
            stage_tile<BN>(bl_g + k0, ldb, Bs_lo, wave, lane);
        }
        __syncthreads();

        s16x8 ah[IM], bh[IN], al[IM], bl[IN];
#pragma unroll
        for (int i = 0; i < IM; ++i) ah[i] = frag_ld(As_hi, wm * TM + i * 16 + rr, kc);
#pragma unroll
        for (int j = 0; j < IN; ++j) bh[j] = frag_ld(Bs_hi, wn * TN + j * 16 + rr, kc);
        if constexpr (SPLIT == 3) {
#pragma unroll
            for (int i = 0; i < IM; ++i) al[i] = frag_ld(As_lo, wm * TM + i * 16 + rr, kc);
#pragma unroll
            for (int j = 0; j < IN; ++j) bl[j] = frag_ld(Bs_lo, wn * TN + j * 16 + rr, kc);
        }

#pragma unroll
        for (int i = 0; i < IM; ++i)
#pragma unroll
            for (int j = 0; j < IN; ++j)
                acc[i][j] = __builtin_amdgcn_mfma_f32_16x16x32_bf16(ah[i], bh[j], acc[i][j], 0, 0, 0);
        if constexpr (SPLIT == 3) {
#pragma unroll
            for (int i = 0; i < IM; ++i)
#pragma unroll
                for (int j = 0; j < IN; ++j)
                    acc[i][j] = __builtin_amdgcn_mfma_f32_16x16x32_bf16(ah[i], bl[j], acc[i][j], 0, 0, 0);
#pragma unroll
            for (int i = 0; i < IM; ++i)
#pragma unroll
                for (int j = 0; j < IN; ++j)
                    acc[i][j] = __builtin_amdgcn_mfma_f32_16x16x32_bf16(al[i], bh[j], acc[i][j], 0, 0, 0);
        }
        __syncthreads();
    }

    // Epilogue: C/D layout col=lane&15, row=(lane>>4)*4+reg
    const int lr = lane >> 4;
    const int lc = lane & 15;
#pragma unroll
    for (int i = 0; i < IM; ++i)
#pragma unroll
        for (int j = 0; j < IN; ++j)
#pragma unroll
            for (int r = 0; r < 4; ++r) {
                const int row = m0 + wm * TM + i * 16 + lr * 4 + r;
                const int col = n0 + wn * TN + j * 16 + lc;
                const float v = acc[i][j][r] * scale;
                const size_t idx = (size_t)row * ldc + col;
                if constexpr (EPI == 0) {
                    C[idx] = v;
                } else if constexpr (EPI == 1) {
                    const unsigned short h = f2bf(v);
                    Chi[idx] = h;
                    Clo[idx] = f2bf(v - bf2f(h));
                } else {
                    C[idx] = v;
                    Chi[idx] = f2bf(v);
                }
            }
}

// ---------------------------------------------------------------------------
// Elementwise fp32 -> (hi, lo) bf16 split.
// ---------------------------------------------------------------------------
__global__ __launch_bounds__(256) void split_convert(const float4* __restrict__ in,
                                                     ushort4* __restrict__ hi,
                                                     ushort4* __restrict__ lo, int n4) {
    for (int idx = blockIdx.x * 256 + threadIdx.x; idx < n4; idx += gridDim.x * 256) {
        const float4 v = in[idx];
        ushort4 h, l;
        h.x = f2bf(v.x); l.x = f2bf(v.x - bf2f(h.x));
        h.y = f2bf(v.y); l.y = f2bf(v.y - bf2f(h.y));
        h.z = f2bf(v.z); l.z = f2bf(v.z - bf2f(h.z));
        h.w = f2bf(v.w); l.w = f2bf(v.w - bf2f(h.w));
        hi[idx] = h; lo[idx] = l;
    }
}

// ---------------------------------------------------------------------------
// Sparse exact softmax + gather:  out[r,:] = softmax(S[r,:])@X restricted to
// candidates l_hat > rowmax - MARGIN, with logits recomputed exactly in fp32.
// One block (256 thr) per row. Dropped softmax mass < 4096*e^-30 (exact).
// ---------------------------------------------------------------------------
#define MARGIN 64.0f
#define MAXCAND 128

__global__ __launch_bounds__(256) void sparse_attn_out(const float* __restrict__ S,
                                                       const float* __restrict__ Qf,
                                                       const float* __restrict__ X,
                                                       float* __restrict__ out) {
    const int t = threadIdx.x;
    const int row = blockIdx.x;
    const float* sp = S + (size_t)row * NTOK;

    __shared__ float red[4];
    __shared__ int   cnt;
    __shared__ int   list[MAXCAND];
    __shared__ float llist[MAXCAND];
    if (t == 0) cnt = 0;

    // load cheap-logit row
    float v[16];
#pragma unroll
    for (int i = 0; i < 4; ++i) {
        const float4 x = *(const float4*)&sp[(t + 256 * i) * 4];
        v[i * 4 + 0] = x.x; v[i * 4 + 1] = x.y;
        v[i * 4 + 2] = x.z; v[i * 4 + 3] = x.w;
    }

    // row max of cheap logits
    float m = -3.4e38f;
#pragma unroll
    for (int j = 0; j < 16; ++j) m = fmaxf(m, v[j]);
#pragma unroll
    for (int off = 32; off >= 1; off >>= 1) m = fmaxf(m, __shfl_xor(m, off, 64));
    if ((t & 63) == 0) red[t >> 6] = m;
    __syncthreads();
    m = fmaxf(fmaxf(red[0], red[1]), fmaxf(red[2], red[3]));

    // candidate collection
    const float thr = m - MARGIN;
#pragma unroll
    for (int i = 0; i < 4; ++i)
#pragma unroll
        for (int e = 0; e < 4; ++e)
            if (v[i * 4 + e] > thr) {
                const int pos = atomicAdd(&cnt, 1);
                if (pos < MAXCAND) list[pos] = (t + 256 * i) * 4 + e;
            }
    __syncthreads();
    const int nc = min(cnt, MAXCAND);

    // exact logits: dot(Q'row_f32, X_j_f32) / 32, cooperative
    const float4 q4 = *(const float4*)&Qf[(size_t)row * EMBED + t * 4];
    for (int c = 0; c < nc; ++c) {
        const int j = list[c];
        const float4 xj = *(const float4*)&X[(size_t)j * EMBED + t * 4];
        float p = q4.x * xj.x + q4.y * xj.y + q4.z * xj.z + q4.w * xj.w;
#pragma unroll
        for (int off = 32; off >= 1; off >>= 1) p += __shfl_xor(p, off, 64);
        __syncthreads();                       // red[] reuse safety
        if ((t & 63) == 0) red[t >> 6] = p;
        __syncthreads();
        if (t == 0) llist[c] = (red[0] + red[1] + red[2] + red[3]) * 0.03125f;
    }
    __syncthreads();

    // exact softmax over candidates
    float mt = -3.4e38f;
    for (int c = 0; c < nc; ++c) mt = fmaxf(mt, llist[c]);
    float wsum = 0.f;
    for (int c = 0; c < nc; ++c) wsum += __expf(llist[c] - mt);
    const float inv = 1.0f / wsum;

    // out row: thread owns 4 cols
    float4 o = {0.f, 0.f, 0.f, 0.f};
    for (int c = 0; c < nc; ++c) {
        const float w = __expf(llist[c] - mt);
        const float4 xj = *(const float4*)&X[(size_t)list[c] * EMBED + t * 4];
        o.x += w * xj.x; o.y += w * xj.y; o.z += w * xj.z; o.w += w * xj.w;
    }
    o.x *= inv; o.y *= inv; o.z *= inv; o.w *= inv;
    *(float4*)&out[(size_t)row * EMBED + t * 4] = o;
}

extern "C" void kernel_launch(void* const* d_in, const int* in_sizes, int n_in,
                              void* d_out, int out_size, void* d_ws, size_t ws_size,
                              hipStream_t stream) {
    const float* X  = (const float*)d_in[0];  // [4096,1024]
    const float* Wq = (const float*)d_in[1];  // [1024,1024]
    const float* Wk = (const float*)d_in[2];  // [1024,1024]
    float* out = (float*)d_out;

    char* ws = (char*)d_ws;
    const size_t MB = 1024 * 1024;
    // Persistent until gather: Xhi [0,8), Q'hi [8,16), Q'f32 [16,32), S [32,96).
    unsigned short* Xhi = (unsigned short*)(ws + 0 * MB);
    unsigned short* Qhi = (unsigned short*)(ws + 8 * MB);
    float*          Qf  = (float*)(ws + 16 * MB);
    float*          S   = (float*)(ws + 32 * MB);
    // Temporaries living inside the future S region (dead before S written):
    unsigned short* Xlo  = (unsigned short*)(ws + 32 * MB);  // dead after Q' gemm
    unsigned short* Wkhi = (unsigned short*)(ws + 40 * MB);
    unsigned short* Wklo = (unsigned short*)(ws + 42 * MB);
    unsigned short* Wqhi = (unsigned short*)(ws + 44 * MB);
    unsigned short* Wqlo = (unsigned short*)(ws + 46 * MB);
    unsigned short* Thi  = (unsigned short*)(ws + 48 * MB);  // T = Wk@Wq^T = M^T
    unsigned short* Tlo  = (unsigned short*)(ws + 50 * MB);

    // 1) elementwise splits (no transposes needed — nt-form GEMMs)
    split_convert<<<4096, 256, 0, stream>>>((const float4*)X, (ushort4*)Xhi,
                                            (ushort4*)Xlo, NTOK * EMBED / 4);
    split_convert<<<1024, 256, 0, stream>>>((const float4*)Wq, (ushort4*)Wqhi,
                                            (ushort4*)Wqlo, EMBED * EMBED / 4);
    split_convert<<<1024, 256, 0, stream>>>((const float4*)Wk, (ushort4*)Wkhi,
                                            (ushort4*)Wklo, EMBED * EMBED / 4);

    // 2) T = Wk @ Wq^T  (= M^T), 3-pass split, split epilogue
    gemm_mfma<64, 64, 3, 1><<<dim3(16, 16), 256, 0, stream>>>(
        Wkhi, Wklo, Wqhi, Wqlo, nullptr, Thi, Tlo, EMBED, EMBED, EMBED, EMBED, 1.0f);

    // 3) Q' = X @ T^T  (= X @ M), 3-pass split, fp32 + bf16-hi epilogue
    gemm_mfma<128, 64, 3, 2><<<dim3(16, 32), 256, 0, stream>>>(
        Xhi, Xlo, Thi, Tlo, Qf, Qhi, nullptr, EMBED, EMBED, EMBED, EMBED, 1.0f);

    // 4) cheap scores: S = (Q'hi @ Xhi^T) / 32, single pass, fp32 out
    gemm_mfma<128, 128, 1, 0><<<dim3(32, 32), 256, 0, stream>>>(
        Qhi, nullptr, Xhi, nullptr, S, nullptr, nullptr, EMBED, EMBED, EMBED, NTOK, 0.03125f);

    // 5) exact sparse softmax-gather
    sparse_attn_out<<<NTOK, 256, 0, stream>>>(S, Qf, X, out);
}